// Round 14
// baseline (226.506 us; speedup 1.0000x reference)
//
#include <hip/hip_runtime.h>
#include <hip/hip_bf16.h>

#define NB 64
#define BATCHES 16
#define ELEMS_PER_BATCH (1024 * 1024)
#define CHUNKS 128                               // blocks per batch
#define CHUNK_ELEMS (ELEMS_PER_BATCH / CHUNKS)   // 8192
#define EPS 1e-8f

__global__ void mi_zero_kernel(unsigned int* __restrict__ hist) {
    int i = threadIdx.x;
    if (i < BATCHES * NB) hist[i] = 0u;
}

// Proven r13 kernel: per-lane-private byte-packed histograms, ds_add atomics.
__global__ __launch_bounds__(256, 8) void mi_hist_kernel(const float* __restrict__ x,
                                                         const float* __restrict__ y,
                                                         unsigned int* __restrict__ hist) {
    __shared__ unsigned int lh[4][NB / 4][64];   // 16 KB
    __shared__ unsigned int rb[4][NB];           // 1 KB

    const int tid  = threadIdx.x;
    const int wave = tid >> 6;
    const int lane = tid & 63;

    for (int i = tid; i < 4 * (NB / 4) * 64 + 4 * NB; i += 256)
        ((unsigned int*)lh)[i] = 0u;
    __syncthreads();

    const int b     = blockIdx.y;
    const long base = (long)b * ELEMS_PER_BATCH + (long)blockIdx.x * CHUNK_ELEMS;
    const float4* __restrict__ x4 = (const float4*)(x + base);
    const float4* __restrict__ y4 = (const float4*)(y + base);

    unsigned int* __restrict__ myrow = &lh[wave][0][lane];

    #pragma unroll
    for (int half = 0; half < 2; ++half) {
        float4 xv[4], yv[4];
        #pragma unroll
        for (int k = 0; k < 4; ++k) {
            int i = tid + (half * 4 + k) * 256;
            xv[k] = x4[i];
            yv[k] = y4[i];
        }
        #pragma unroll
        for (int k = 0; k < 4; ++k) {
            #pragma unroll
            for (int c = 0; c < 4; ++c) {
                float xc = (&xv[k].x)[c];
                float yc = (&yv[k].x)[c];
                float v = __fadd_rn(__fmul_rn(xc, 64.0f), yc);   // no FMA: match numpy
                if (v >= 0.0f && v <= 64.0f) {
                    int idx = (int)v;                 // v >= 0: floor == trunc
                    if (idx > NB - 1) idx = NB - 1;   // v == 64 -> last bin
                    atomicAdd(myrow + (idx >> 2) * 64, 1u << ((idx & 3) << 3));
                }
            }
        }
    }
    __syncthreads();

    if (lane < 16) {
        unsigned int a0 = 0, a1 = 0, a2 = 0, a3 = 0;
        #pragma unroll
        for (int j = 0; j < 64; ++j) {
            unsigned int vv = lh[wave][lane][(j + lane) & 63];
            a0 += vv & 0xffu;
            a1 += (vv >> 8) & 0xffu;
            a2 += (vv >> 16) & 0xffu;
            a3 += vv >> 24;
        }
        rb[wave][4 * lane]     = a0;
        rb[wave][4 * lane + 1] = a1;
        rb[wave][4 * lane + 2] = a2;
        rb[wave][4 * lane + 3] = a3;
    }
    __syncthreads();

    if (tid < NB) {
        unsigned int s = rb[0][tid] + rb[1][tid] + rb[2][tid] + rb[3][tid];
        atomicAdd(&hist[b * NB + tid], s);
    }
}

// DISCRIMINATOR: identical structure, NON-ATOMIC read-modify-write (legal:
// each lane owns its column; DS ops from one wave execute in program order).
// REPS=4 with rotating chunk so dispatches exceed the 46us control and land
// in the top-5 (observed/4 = per-pass cost). u8 fields reach max 4*32=128<256.
#define RMW_REPS 4
__global__ __launch_bounds__(256, 8) void mi_hist_rmw(const float* __restrict__ x,
                                                      const float* __restrict__ y,
                                                      unsigned int* __restrict__ hist2) {
    __shared__ unsigned int lh[4][NB / 4][64];   // 16 KB
    __shared__ unsigned int rb[4][NB];           // 1 KB

    const int tid  = threadIdx.x;
    const int wave = tid >> 6;
    const int lane = tid & 63;

    for (int i = tid; i < 4 * (NB / 4) * 64 + 4 * NB; i += 256)
        ((unsigned int*)lh)[i] = 0u;
    __syncthreads();

    const int b = blockIdx.y;
    unsigned int* __restrict__ myrow = &lh[wave][0][lane];

    #pragma unroll 1
    for (int rep = 0; rep < RMW_REPS; ++rep) {
        // rotate chunk per rep: defeats cross-rep load CSE, same total footprint
        const int cx    = (blockIdx.x + rep * 37) & (CHUNKS - 1);
        const long base = (long)b * ELEMS_PER_BATCH + (long)cx * CHUNK_ELEMS;
        const float4* __restrict__ x4 = (const float4*)(x + base);
        const float4* __restrict__ y4 = (const float4*)(y + base);

        #pragma unroll
        for (int half = 0; half < 2; ++half) {
            float4 xv[4], yv[4];
            #pragma unroll
            for (int k = 0; k < 4; ++k) {
                int i = tid + (half * 4 + k) * 256;
                xv[k] = x4[i];
                yv[k] = y4[i];
            }
            #pragma unroll
            for (int k = 0; k < 4; ++k) {
                #pragma unroll
                for (int c = 0; c < 4; ++c) {
                    float xc = (&xv[k].x)[c];
                    float yc = (&yv[k].x)[c];
                    float v = __fadd_rn(__fmul_rn(xc, 64.0f), yc);
                    if (v >= 0.0f && v <= 64.0f) {
                        int idx = (int)v;
                        if (idx > NB - 1) idx = NB - 1;
                        unsigned int* p = myrow + (idx >> 2) * 64;
                        *p = *p + (1u << ((idx & 3) << 3));   // ds_read+add+ds_write
                    }
                }
            }
        }
    }
    __syncthreads();

    if (lane < 16) {
        unsigned int a0 = 0, a1 = 0, a2 = 0, a3 = 0;
        #pragma unroll
        for (int j = 0; j < 64; ++j) {
            unsigned int vv = lh[wave][lane][(j + lane) & 63];
            a0 += vv & 0xffu;
            a1 += (vv >> 8) & 0xffu;
            a2 += (vv >> 16) & 0xffu;
            a3 += vv >> 24;
        }
        rb[wave][4 * lane]     = a0;
        rb[wave][4 * lane + 1] = a1;
        rb[wave][4 * lane + 2] = a2;
        rb[wave][4 * lane + 3] = a3;
    }
    __syncthreads();

    if (tid < NB) {
        unsigned int s = rb[0][tid] + rb[1][tid] + rb[2][tid] + rb[3][tid];
        atomicAdd(&hist2[b * NB + tid], s);
    }
}

// One block: 16 waves, wave b handles batch b, lane k handles bin k.
__global__ __launch_bounds__(1024) void mi_final_kernel(const unsigned int* __restrict__ hist,
                                                        float* __restrict__ out) {
    const int tid = threadIdx.x;
    const int b   = tid >> 6;
    const int k   = tid & 63;

    float h = (float)hist[b * NB + k];

    float s = h;
    #pragma unroll
    for (int off = 32; off >= 1; off >>= 1) s += __shfl_xor(s, off, 64);

    float jp = h / s + EPS;

    float p = jp;
    #pragma unroll
    for (int off = 32; off >= 1; off >>= 1) p += __shfl_xor(p, off, 64);

    float term = jp * logf(jp / (p * p));
    float t = term;
    #pragma unroll
    for (int off = 32; off >= 1; off >>= 1) t += __shfl_xor(t, off, 64);

    __shared__ float mi[BATCHES];
    if (k == 0) mi[b] = t;
    __syncthreads();

    if (tid == 0) {
        float acc = 0.0f;
        #pragma unroll
        for (int i = 0; i < BATCHES; ++i) acc += mi[i];
        *out = -acc / (float)BATCHES;
    }
}

extern "C" void kernel_launch(void* const* d_in, const int* in_sizes, int n_in,
                              void* d_out, int out_size, void* d_ws, size_t ws_size,
                              hipStream_t stream) {
    const float* x = (const float*)d_in[0];
    const float* y = (const float*)d_in[1];
    float* out = (float*)d_out;
    unsigned int* hist  = (unsigned int*)d_ws;
    unsigned int* hist2 = hist + BATCHES * NB;

    mi_zero_kernel<<<1, 1024, 0, stream>>>(hist);

    dim3 grid(CHUNKS, BATCHES);
    mi_hist_kernel<<<grid, 256, 0, stream>>>(x, y, hist);

    mi_final_kernel<<<1, 1024, 0, stream>>>(hist, out);

    // Discriminator (after `out` is produced; writes only scratch hist2).
    if (ws_size >= 2 * BATCHES * NB * sizeof(unsigned int)) {
        mi_hist_rmw<<<grid, 256, 0, stream>>>(x, y, hist2);
    }
}